// Round 7
// baseline (498.289 us; speedup 1.0000x reference)
//
#include <hip/hip_runtime.h>
#include <math.h>

#define F 64
#define VIOL_THRESH 0.2f
#define BLK_NODES 128
#define H_ROWB 272   // 136 bf16 per row: 68 words ≡ 4 mod 32 banks -> 2-way (free)

typedef float  f32x4  __attribute__((ext_vector_type(4)));
typedef short  bf16x8 __attribute__((ext_vector_type(8)));

__device__ __forceinline__ short f2bf(float f) {
    unsigned u = __builtin_bit_cast(unsigned, f);
    unsigned r = (u + 0x7fffu + ((u >> 16) & 1u)) >> 16;
    return (short)r;
}

__global__ void init_kernel(unsigned long long* __restrict__ pairs,
                            float* __restrict__ accf, int* __restrict__ acci,
                            int n, unsigned long long sent) {
    int i = blockIdx.x * blockDim.x + threadIdx.x;
    if (i < n) pairs[i] = sent;
    if (i == 0) { accf[0] = 0.f; accf[1] = 0.f; acci[0] = 0; }
}

// fp32 features -> bf16 (one-time pass; node kernel then gathers 128B rows)
__global__ void prep_feat(const float* __restrict__ f, short* __restrict__ fb, long total) {
    long t = (long)blockIdx.x * blockDim.x + threadIdx.x;
    long base = t * 8;
    if (base >= total) return;
    float4 a = *(const float4*)(f + base);
    float4 b = *(const float4*)(f + base + 4);
    bf16x8 o;
    o[0] = f2bf(a.x); o[1] = f2bf(a.y); o[2] = f2bf(a.z); o[3] = f2bf(a.w);
    o[4] = f2bf(b.x); o[5] = f2bf(b.y); o[6] = f2bf(b.z); o[7] = f2bf(b.w);
    *(bf16x8*)(fb + base) = o;
}

// wt1t[o][k]: o in [0,128) (64 rc | 64 cp), k in [0,192)
__global__ void prep_w1(const float* __restrict__ w1rc, const float* __restrict__ w1cp,
                        short* __restrict__ wt1t) {
    int o = blockIdx.x;                      // 0..127
    int k = blockIdx.y * 64 + threadIdx.x;   // 0..191
    const float* src = (o < 64) ? (w1rc + o) : (w1cp + (o - 64));
    wt1t[o * 192 + k] = f2bf(src[(size_t)k * 64]);
}

// wt2t[o][k_perm]: 48 x 128 block-diagonal, k permuted to match packed-H layout:
// k_perm = (k&15)*8 + (k>>4)  (dot over k is permutation-invariant)
__global__ void prep_w2(const float* __restrict__ w2rc, const float* __restrict__ w2cp,
                        short* __restrict__ wt2t) {
    int o = blockIdx.x;                      // 0..47
    int k = blockIdx.y * 64 + threadIdx.x;   // 0..127
    float v = 0.f;
    if (o < 32)       { if (k < 64) v = w2rc[k * 32 + o]; }
    else if (o == 32) { if (k >= 64) v = w2cp[k - 64]; }
    int kp = (k & 15) * 8 + (k >> 4);
    wt2t[o * 128 + kp] = f2bf(v);
}

__device__ __forceinline__ void ins2(unsigned long long* __restrict__ p, unsigned v) {
    unsigned long long cur = *p;             // stale-tolerant (monotone decreasing)
    while (true) {
        unsigned m1 = (unsigned)(cur >> 32);
        unsigned m2 = (unsigned)cur;
        unsigned nm1, nm2;
        if (v < m1)                   { nm1 = v;  nm2 = m1; }
        else if (v != m1 && v < m2)   { nm1 = m1; nm2 = v;  }
        else return;
        unsigned long long nw = ((unsigned long long)nm1 << 32) | nm2;
        unsigned long long prev = atomicCAS(p, cur, nw);
        if (prev == cur) return;
        cur = prev;
    }
}

__global__ void edge_pair_kernel(const int* __restrict__ e0, const int* __restrict__ e1,
                                 unsigned long long* __restrict__ pairs, int m) {
    int t = blockIdx.x * blockDim.x + threadIdx.x;
    int base = t * 4;
    if (base >= m) return;
    if (base + 4 <= m) {
        int4 u4 = *(const int4*)(e0 + base);
        int4 v4 = *(const int4*)(e1 + base);
        if (u4.x != v4.x) { ins2(&pairs[u4.x], v4.x); ins2(&pairs[v4.x], u4.x); }
        if (u4.y != v4.y) { ins2(&pairs[u4.y], v4.y); ins2(&pairs[v4.y], u4.y); }
        if (u4.z != v4.z) { ins2(&pairs[u4.z], v4.z); ins2(&pairs[v4.z], u4.z); }
        if (u4.w != v4.w) { ins2(&pairs[u4.w], v4.w); ins2(&pairs[v4.w], u4.w); }
    } else {
        for (int j = base; j < m; j++) {
            int u = e0[j], v = e1[j];
            if (u != v) { ins2(&pairs[u], v); ins2(&pairs[v], u); }
        }
    }
}

template<bool BF>
__global__ __launch_bounds__(256)
void node_kernel(const float* __restrict__ feat, const short* __restrict__ featbf,
                 const float* __restrict__ radii,
                 const float* __restrict__ b1rc, const float* __restrict__ b2rc,
                 const float* __restrict__ w3rc, const float* __restrict__ b3rc,
                 const float* __restrict__ b1cp, const float* __restrict__ b2cp,
                 const short* __restrict__ wt1t, const short* __restrict__ wt2t,
                 const int* __restrict__ types,
                 const unsigned long long* __restrict__ pairs,
                 float* __restrict__ gates, float* __restrict__ accf, int* __restrict__ acci,
                 int n) {
    __shared__ __align__(16) char Hbuf[BLK_NODES * H_ROWB];   // 34816 B
    __shared__ float corrArr[BLK_NODES];
    __shared__ float zArr[BLK_NODES];

    int tid = threadIdx.x;
    int blk = blockIdx.x;
    int lane = tid & 63;
    int w = tid >> 6;
    int lm = lane & 15;
    int lg = lane >> 4;
    int wnb = w * 32;

    // node ids per (m-tile, part)
    int nid[2][3];
#pragma unroll
    for (int mt = 0; mt < 2; mt++) {
        int g = blk * BLK_NODES + wnb + mt * 16 + lm;
        int ii = (g < n) ? g : (n - 1);
        unsigned long long pr = pairs[ii];
        int m1 = (int)(pr >> 32);
        int m2 = (int)(unsigned)pr;
        nid[mt][0] = ii;
        nid[mt][1] = (m1 < n) ? m1 : (n - 1);
        nid[mt][2] = (m2 < n) ? m2 : (n - 1);
    }

    // ---------- prefetch ALL layer-1 A-fragments (12 x 16B, all in flight) ----------
    bf16x8 af[2][3][2];
    if constexpr (BF) {
#pragma unroll
        for (int mt = 0; mt < 2; mt++)
#pragma unroll
            for (int part = 0; part < 3; part++)
#pragma unroll
                for (int h = 0; h < 2; h++)
                    af[mt][part][h] = *(const bf16x8*)(featbf + (size_t)nid[mt][part] * F + h * 32 + lg * 8);
    }

    // ---------- layer 1: H[128 nodes][128 outs] ----------
    f32x4 zero4 = {0.f, 0.f, 0.f, 0.f};
    f32x4 acc[2][8];
#pragma unroll
    for (int mt = 0; mt < 2; mt++)
#pragma unroll
        for (int nt = 0; nt < 8; nt++) acc[mt][nt] = zero4;

#pragma unroll
    for (int s = 0; s < 6; s++) {
        int part = s >> 1;
        int h = s & 1;
        bf16x8 a0, a1;
        if constexpr (BF) {
            a0 = af[0][part][h];
            a1 = af[1][part][h];
        } else {
#pragma unroll
            for (int mt = 0; mt < 2; mt++) {
                const float* rp = feat + (size_t)nid[mt][part] * F + h * 32 + lg * 8;
                float4 f0 = *(const float4*)rp;
                float4 f1 = *(const float4*)(rp + 4);
                bf16x8 a;
                a[0] = f2bf(f0.x); a[1] = f2bf(f0.y); a[2] = f2bf(f0.z); a[3] = f2bf(f0.w);
                a[4] = f2bf(f1.x); a[5] = f2bf(f1.y); a[6] = f2bf(f1.z); a[7] = f2bf(f1.w);
                if (mt == 0) a0 = a; else a1 = a;
            }
        }
#pragma unroll
        for (int nt = 0; nt < 8; nt++) {
            bf16x8 b = *(const bf16x8*)(wt1t + (lm + 16 * nt) * 192 + s * 32 + lg * 8);
            acc[0][nt] = __builtin_amdgcn_mfma_f32_16x16x32_bf16(a0, b, acc[0][nt], 0, 0, 0);
            acc[1][nt] = __builtin_amdgcn_mfma_f32_16x16x32_bf16(a1, b, acc[1][nt], 0, 0, 0);
        }
    }

    // biases for this lane's 8 output columns (o = lm + 16*nt)
    float b1v[8];
#pragma unroll
    for (int nt = 0; nt < 8; nt++)
        b1v[nt] = (nt < 4) ? b1rc[lm + 16 * nt] : b1cp[lm + 16 * nt - 64];

    // packed H store: row layout o_perm = lm*8 + nt  -> one ds_write_b128 per (mt,r)
#pragma unroll
    for (int mt = 0; mt < 2; mt++) {
#pragma unroll
        for (int r = 0; r < 4; r++) {
            int node = wnb + mt * 16 + lg * 4 + r;
            bf16x8 hv;
#pragma unroll
            for (int nt = 0; nt < 8; nt++)
                hv[nt] = f2bf(fmaxf(acc[mt][nt][r] + b1v[nt], 0.f));
            *(bf16x8*)(Hbuf + node * H_ROWB + lm * 16) = hv;
        }
    }
    __syncthreads();

    // ---------- layer 2: [128 nodes][33 of 48] (k in permuted order both sides) ----------
    f32x4 acc2[2][3];
#pragma unroll
    for (int mt = 0; mt < 2; mt++)
#pragma unroll
        for (int nt = 0; nt < 3; nt++) acc2[mt][nt] = zero4;

#pragma unroll
    for (int s = 0; s < 4; s++) {
        bf16x8 af2[2];
#pragma unroll
        for (int mt = 0; mt < 2; mt++)
            af2[mt] = *(const bf16x8*)(Hbuf + (wnb + mt * 16 + lm) * H_ROWB + s * 64 + lg * 16);
#pragma unroll
        for (int nt = 0; nt < 3; nt++) {
            bf16x8 b = *(const bf16x8*)(wt2t + (lm + 16 * nt) * 128 + s * 32 + lg * 8);
            acc2[0][nt] = __builtin_amdgcn_mfma_f32_16x16x32_bf16(af2[0], b, acc2[0][nt], 0, 0, 0);
            acc2[1][nt] = __builtin_amdgcn_mfma_f32_16x16x32_bf16(af2[1], b, acc2[1][nt], 0, 0, 0);
        }
    }

    // corr / z per node
#pragma unroll
    for (int mt = 0; mt < 2; mt++) {
#pragma unroll
        for (int r = 0; r < 4; r++) {
            float t = 0.f;
#pragma unroll
            for (int nt = 0; nt < 2; nt++) {
                int o = lm + 16 * nt;
                float s2v = fmaxf(acc2[mt][nt][r] + b2rc[o], 0.f);
                t = fmaf(s2v, w3rc[o], t);
            }
            float zz = acc2[mt][2][r];   // only o==32 (lm==0) nonzero; rest exact zeros
#pragma unroll
            for (int msk = 1; msk < 16; msk <<= 1) {
                t  += __shfl_xor(t, msk);
                zz += __shfl_xor(zz, msk);
            }
            if (lm == 0) {
                int node = wnb + mt * 16 + lg * 4 + r;
                corrArr[node] = t + b3rc[0];
                zArr[node]    = zz + b2cp[0];
            }
        }
    }
    __syncthreads();

    // ---------- epilogue: viol / gate / averages (gates -> global) ----------
    float sv = 0.f, sc = 0.f; int ct = 0;
    if (tid < BLK_NODES) {
        int g = blk * BLK_NODES + tid;
        bool live = g < n;
        int ii = live ? g : (n - 1);
        unsigned long long pr = pairs[ii];
        int m1 = (int)(pr >> 32);
        int m2 = (int)(unsigned)pr;
        bool valid = m2 < n;
        int c1 = (m1 < n) ? m1 : (n - 1);
        int c2 = (m2 < n) ? m2 : (n - 1);
        float rp_ = radii[ii], r1_ = radii[c1], r2_ = radii[c2];
        float pr3 = rp_ * rp_ * rp_;
        float viol = fabsf(r1_ * r1_ * r1_ + r2_ * r2_ * r2_ - pr3) / pr3;
        bool active = live && valid && (types[ii] == 1);
        bool upd = active && (viol > VIOL_THRESH);
        float gate = upd ? corrArr[tid] : 0.f;
        if (live) gates[g] = 0.1f * gate;
        if (active) {
            sv = viol;
            sc = 1.0f / (1.0f + expf(-zArr[tid]));
            ct = 1;
        }
    }
#pragma unroll
    for (int off = 32; off > 0; off >>= 1) {
        sv += __shfl_down(sv, off);
        sc += __shfl_down(sc, off);
        ct += __shfl_down(ct, off);
    }
    if (lane == 0 && (sv != 0.f || sc != 0.f || ct != 0)) {
        atomicAdd(&accf[0], sv);
        atomicAdd(&accf[1], sc);
        atomicAdd(acci, ct);
    }
}

// pure streaming: out = feat + gates[node] * tanh(feat)
__global__ __launch_bounds__(256)
void update_kernel(const float* __restrict__ feat, const float* __restrict__ gates,
                   float* __restrict__ out, long total4) {
    long stride = (long)gridDim.x * blockDim.x;
    for (long t = (long)blockIdx.x * blockDim.x + threadIdx.x; t < total4; t += stride) {
        long base = t * 4;
        int node = (int)(base >> 6);          // F=64 floats per node
        float g = gates[node];
        float4 v = *(const float4*)(feat + base);
        float4 r;
        r.x = v.x + g * tanhf(v.x);
        r.y = v.y + g * tanhf(v.y);
        r.z = v.z + g * tanhf(v.z);
        r.w = v.w + g * tanhf(v.w);
        *(float4*)(out + base) = r;
    }
}

__global__ void finalize_kernel(const float* __restrict__ accf, const int* __restrict__ acci,
                                float* __restrict__ out_scalars) {
    if (threadIdx.x == 0) {
        int c = acci[0];
        float d = (float)(c > 1 ? c : 1);
        out_scalars[0] = accf[0] / d;
        out_scalars[1] = accf[1] / d;
    }
}

extern "C" void kernel_launch(void* const* d_in, const int* in_sizes, int n_in,
                              void* d_out, int out_size, void* d_ws, size_t ws_size,
                              hipStream_t stream) {
    const float* feat  = (const float*)d_in[0];
    const float* radii = (const float*)d_in[1];
    const float* w1rc  = (const float*)d_in[2];
    const float* b1rc  = (const float*)d_in[3];
    const float* w2rc  = (const float*)d_in[4];
    const float* b2rc  = (const float*)d_in[5];
    const float* w3rc  = (const float*)d_in[6];
    const float* b3rc  = (const float*)d_in[7];
    const float* w1cp  = (const float*)d_in[8];
    const float* b1cp  = (const float*)d_in[9];
    const float* w2cp  = (const float*)d_in[10];
    const float* b2cp  = (const float*)d_in[11];
    const int*   eidx  = (const int*)d_in[12];
    const int*   types = (const int*)d_in[13];

    int n = in_sizes[0] / F;          // 300000
    int m = in_sizes[12] / 2;         // 3000000

    // ws layout: wt1t | wt2t | pairs | accf | acci | gates | featbf
    char* ws = (char*)d_ws;
    short* wt1t = (short*)ws;                            ws += 128 * 192 * 2;
    short* wt2t = (short*)ws;                            ws += 48 * 128 * 2;
    unsigned long long* pairs = (unsigned long long*)ws; ws += (size_t)n * 8;
    float* accf = (float*)ws;                            ws += 8;
    int*   acci = (int*)ws;                              ws += 8;   // keep 16B align
    float* gates = (float*)ws;                           ws += (size_t)n * 4;
    short* featbf = (short*)ws;
    size_t featbf_bytes = (size_t)n * F * 2;
    bool useBF = ((size_t)(ws - (char*)d_ws) + featbf_bytes) <= ws_size;

    float* out         = (float*)d_out;
    float* out_scalars = out + (size_t)n * F;

    unsigned long long sent = ((unsigned long long)(unsigned)n << 32) | (unsigned)n;

    int bs = 256;
    init_kernel<<<(n + bs - 1) / bs, bs, 0, stream>>>(pairs, accf, acci, n, sent);
    prep_w1<<<dim3(128, 3), 64, 0, stream>>>(w1rc, w1cp, wt1t);
    prep_w2<<<dim3(48, 2), 64, 0, stream>>>(w2rc, w2cp, wt2t);
    if (useBF) {
        long total = (long)n * F;
        long nthr = total / 8;
        prep_feat<<<(unsigned)((nthr + bs - 1) / bs), bs, 0, stream>>>(feat, featbf, total);
    }
    int mt = (m + 3) / 4;
    edge_pair_kernel<<<(mt + bs - 1) / bs, bs, 0, stream>>>(eidx, eidx + m, pairs, m);
    int nblocks = (n + BLK_NODES - 1) / BLK_NODES;
    if (useBF) {
        node_kernel<true><<<nblocks, bs, 0, stream>>>(
            feat, featbf, radii, b1rc, b2rc, w3rc, b3rc, b1cp, b2cp,
            wt1t, wt2t, types, pairs, gates, accf, acci, n);
    } else {
        node_kernel<false><<<nblocks, bs, 0, stream>>>(
            feat, featbf, radii, b1rc, b2rc, w3rc, b3rc, b1cp, b2cp,
            wt1t, wt2t, types, pairs, gates, accf, acci, n);
    }
    long total4 = (long)n * F / 4;
    update_kernel<<<2048, bs, 0, stream>>>(feat, gates, out, total4);
    finalize_kernel<<<1, 64, 0, stream>>>(accf, acci, out_scalars);
}

// Round 8
// 375.418 us; speedup vs baseline: 1.3273x; 1.3273x over previous
//
#include <hip/hip_runtime.h>
#include <math.h>

#define F 64
#define VIOL_THRESH 0.2f
#define BLK_NODES 128
#define H_ROWB 272   // 136 bf16 per row: 68 words ≡ 4 mod 32 banks -> 2-way (free)

typedef float  f32x4  __attribute__((ext_vector_type(4)));
typedef short  bf16x8 __attribute__((ext_vector_type(8)));

__device__ __forceinline__ short f2bf(float f) {
    unsigned u = __builtin_bit_cast(unsigned, f);
    unsigned r = (u + 0x7fffu + ((u >> 16) & 1u)) >> 16;
    return (short)r;
}

__global__ void init_kernel(unsigned long long* __restrict__ pairs,
                            int n, unsigned long long sent) {
    int i = blockIdx.x * blockDim.x + threadIdx.x;
    if (i < n) pairs[i] = sent;
}

// fp32 features -> bf16 (one-time pass; node kernel then gathers 128B rows)
__global__ void prep_feat(const float* __restrict__ f, short* __restrict__ fb, long total) {
    long t = (long)blockIdx.x * blockDim.x + threadIdx.x;
    long base = t * 8;
    if (base >= total) return;
    float4 a = *(const float4*)(f + base);
    float4 b = *(const float4*)(f + base + 4);
    bf16x8 o;
    o[0] = f2bf(a.x); o[1] = f2bf(a.y); o[2] = f2bf(a.z); o[3] = f2bf(a.w);
    o[4] = f2bf(b.x); o[5] = f2bf(b.y); o[6] = f2bf(b.z); o[7] = f2bf(b.w);
    *(bf16x8*)(fb + base) = o;
}

// wt1t[o][k]: o in [0,128) (64 rc | 64 cp), k in [0,192)
__global__ void prep_w1(const float* __restrict__ w1rc, const float* __restrict__ w1cp,
                        short* __restrict__ wt1t) {
    int o = blockIdx.x;                      // 0..127
    int k = blockIdx.y * 64 + threadIdx.x;   // 0..191
    const float* src = (o < 64) ? (w1rc + o) : (w1cp + (o - 64));
    wt1t[o * 192 + k] = f2bf(src[(size_t)k * 64]);
}

// wt2t[o][k_perm]: 48 x 128 block-diagonal, k permuted to match packed-H layout:
// k_perm = (k&15)*8 + (k>>4)  (dot over k is permutation-invariant)
__global__ void prep_w2(const float* __restrict__ w2rc, const float* __restrict__ w2cp,
                        short* __restrict__ wt2t) {
    int o = blockIdx.x;                      // 0..47
    int k = blockIdx.y * 64 + threadIdx.x;   // 0..127
    float v = 0.f;
    if (o < 32)       { if (k < 64) v = w2rc[k * 32 + o]; }
    else if (o == 32) { if (k >= 64) v = w2cp[k - 64]; }
    int kp = (k & 15) * 8 + (k >> 4);
    wt2t[o * 128 + kp] = f2bf(v);
}

__device__ __forceinline__ void ins2(unsigned long long* __restrict__ p, unsigned v) {
    unsigned long long cur = *p;             // stale-tolerant (monotone decreasing)
    while (true) {
        unsigned m1 = (unsigned)(cur >> 32);
        unsigned m2 = (unsigned)cur;
        unsigned nm1, nm2;
        if (v < m1)                   { nm1 = v;  nm2 = m1; }
        else if (v != m1 && v < m2)   { nm1 = m1; nm2 = v;  }
        else return;
        unsigned long long nw = ((unsigned long long)nm1 << 32) | nm2;
        unsigned long long prev = atomicCAS(p, cur, nw);
        if (prev == cur) return;
        cur = prev;
    }
}

__global__ void edge_pair_kernel(const int* __restrict__ e0, const int* __restrict__ e1,
                                 unsigned long long* __restrict__ pairs, int m) {
    int t = blockIdx.x * blockDim.x + threadIdx.x;
    int base = t * 4;
    if (base >= m) return;
    if (base + 4 <= m) {
        int4 u4 = *(const int4*)(e0 + base);
        int4 v4 = *(const int4*)(e1 + base);
        if (u4.x != v4.x) { ins2(&pairs[u4.x], v4.x); ins2(&pairs[v4.x], u4.x); }
        if (u4.y != v4.y) { ins2(&pairs[u4.y], v4.y); ins2(&pairs[v4.y], u4.y); }
        if (u4.z != v4.z) { ins2(&pairs[u4.z], v4.z); ins2(&pairs[v4.z], u4.z); }
        if (u4.w != v4.w) { ins2(&pairs[u4.w], v4.w); ins2(&pairs[v4.w], u4.w); }
    } else {
        for (int j = base; j < m; j++) {
            int u = e0[j], v = e1[j];
            if (u != v) { ins2(&pairs[u], v); ins2(&pairs[v], u); }
        }
    }
}

template<bool BF>
__global__ __launch_bounds__(256)
void node_kernel(const float* __restrict__ feat, const short* __restrict__ featbf,
                 const float* __restrict__ radii,
                 const float* __restrict__ b1rc, const float* __restrict__ b2rc,
                 const float* __restrict__ w3rc, const float* __restrict__ b3rc,
                 const float* __restrict__ b1cp, const float* __restrict__ b2cp,
                 const short* __restrict__ wt1t, const short* __restrict__ wt2t,
                 const int* __restrict__ types,
                 const unsigned long long* __restrict__ pairs,
                 float* __restrict__ gates, float4* __restrict__ partials,
                 int n) {
    // NOTE: no __syncthreads in this kernel. Each wave touches ONLY its own
    // 32-node slice of Hbuf/corrArr/zArr; within-wave DS ordering is
    // guaranteed by the in-order LDS pipe + compiler lgkmcnt waits.
    __shared__ __align__(16) char Hbuf[BLK_NODES * H_ROWB];   // 34816 B
    __shared__ float corrArr[BLK_NODES];
    __shared__ float zArr[BLK_NODES];

    int tid = threadIdx.x;
    int blk = blockIdx.x;
    int lane = tid & 63;
    int w = tid >> 6;
    int lm = lane & 15;
    int lg = lane >> 4;
    int wnb = w * 32;

    // node ids per (m-tile, part)
    int nid[2][3];
#pragma unroll
    for (int mt = 0; mt < 2; mt++) {
        int g = blk * BLK_NODES + wnb + mt * 16 + lm;
        int ii = (g < n) ? g : (n - 1);
        unsigned long long pr = pairs[ii];
        int m1 = (int)(pr >> 32);
        int m2 = (int)(unsigned)pr;
        nid[mt][0] = ii;
        nid[mt][1] = (m1 < n) ? m1 : (n - 1);
        nid[mt][2] = (m2 < n) ? m2 : (n - 1);
    }

    // ---------- prefetch ALL layer-1 A-fragments (12 x 16B, all in flight) ----------
    bf16x8 af[2][3][2];
    if constexpr (BF) {
#pragma unroll
        for (int mt = 0; mt < 2; mt++)
#pragma unroll
            for (int part = 0; part < 3; part++)
#pragma unroll
                for (int h = 0; h < 2; h++)
                    af[mt][part][h] = *(const bf16x8*)(featbf + (size_t)nid[mt][part] * F + h * 32 + lg * 8);
    }

    // ---------- layer 1: H[32 nodes][128 outs] per wave ----------
    f32x4 zero4 = {0.f, 0.f, 0.f, 0.f};
    f32x4 acc[2][8];
#pragma unroll
    for (int mt = 0; mt < 2; mt++)
#pragma unroll
        for (int nt = 0; nt < 8; nt++) acc[mt][nt] = zero4;

#pragma unroll
    for (int s = 0; s < 6; s++) {
        int part = s >> 1;
        int h = s & 1;
        bf16x8 a0, a1;
        if constexpr (BF) {
            a0 = af[0][part][h];
            a1 = af[1][part][h];
        } else {
#pragma unroll
            for (int mt = 0; mt < 2; mt++) {
                const float* rp = feat + (size_t)nid[mt][part] * F + h * 32 + lg * 8;
                float4 f0 = *(const float4*)rp;
                float4 f1 = *(const float4*)(rp + 4);
                bf16x8 a;
                a[0] = f2bf(f0.x); a[1] = f2bf(f0.y); a[2] = f2bf(f0.z); a[3] = f2bf(f0.w);
                a[4] = f2bf(f1.x); a[5] = f2bf(f1.y); a[6] = f2bf(f1.z); a[7] = f2bf(f1.w);
                if (mt == 0) a0 = a; else a1 = a;
            }
        }
#pragma unroll
        for (int nt = 0; nt < 8; nt++) {
            bf16x8 b = *(const bf16x8*)(wt1t + (lm + 16 * nt) * 192 + s * 32 + lg * 8);
            acc[0][nt] = __builtin_amdgcn_mfma_f32_16x16x32_bf16(a0, b, acc[0][nt], 0, 0, 0);
            acc[1][nt] = __builtin_amdgcn_mfma_f32_16x16x32_bf16(a1, b, acc[1][nt], 0, 0, 0);
        }
    }

    // biases for this lane's 8 output columns (o = lm + 16*nt)
    float b1v[8];
#pragma unroll
    for (int nt = 0; nt < 8; nt++)
        b1v[nt] = (nt < 4) ? b1rc[lm + 16 * nt] : b1cp[lm + 16 * nt - 64];

    // packed H store: row layout o_perm = lm*8 + nt  -> one ds_write_b128 per (mt,r)
#pragma unroll
    for (int mt = 0; mt < 2; mt++) {
#pragma unroll
        for (int r = 0; r < 4; r++) {
            int node = wnb + mt * 16 + lg * 4 + r;
            bf16x8 hv;
#pragma unroll
            for (int nt = 0; nt < 8; nt++)
                hv[nt] = f2bf(fmaxf(acc[mt][nt][r] + b1v[nt], 0.f));
            *(bf16x8*)(Hbuf + node * H_ROWB + lm * 16) = hv;
        }
    }

    // ---------- layer 2: [32 nodes][33 of 48] (k in permuted order both sides) ----------
    f32x4 acc2[2][3];
#pragma unroll
    for (int mt = 0; mt < 2; mt++)
#pragma unroll
        for (int nt = 0; nt < 3; nt++) acc2[mt][nt] = zero4;

#pragma unroll
    for (int s = 0; s < 4; s++) {
        bf16x8 af2[2];
#pragma unroll
        for (int mt = 0; mt < 2; mt++)
            af2[mt] = *(const bf16x8*)(Hbuf + (wnb + mt * 16 + lm) * H_ROWB + s * 64 + lg * 16);
#pragma unroll
        for (int nt = 0; nt < 3; nt++) {
            bf16x8 b = *(const bf16x8*)(wt2t + (lm + 16 * nt) * 128 + s * 32 + lg * 8);
            acc2[0][nt] = __builtin_amdgcn_mfma_f32_16x16x32_bf16(af2[0], b, acc2[0][nt], 0, 0, 0);
            acc2[1][nt] = __builtin_amdgcn_mfma_f32_16x16x32_bf16(af2[1], b, acc2[1][nt], 0, 0, 0);
        }
    }

    // corr / z per node (within-wave shfl reduce, stash in wave's LDS slice)
#pragma unroll
    for (int mt = 0; mt < 2; mt++) {
#pragma unroll
        for (int r = 0; r < 4; r++) {
            float t = 0.f;
#pragma unroll
            for (int nt = 0; nt < 2; nt++) {
                int o = lm + 16 * nt;
                float s2v = fmaxf(acc2[mt][nt][r] + b2rc[o], 0.f);
                t = fmaf(s2v, w3rc[o], t);
            }
            float zz = acc2[mt][2][r];   // only o==32 (lm==0) nonzero; rest exact zeros
#pragma unroll
            for (int msk = 1; msk < 16; msk <<= 1) {
                t  += __shfl_xor(t, msk);
                zz += __shfl_xor(zz, msk);
            }
            if (lm == 0) {
                int node = wnb + mt * 16 + lg * 4 + r;
                corrArr[node] = t + b3rc[0];
                zArr[node]    = zz + b2cp[0];
            }
        }
    }

    // ---------- per-wave epilogue: lanes 0..31 handle the wave's 32 nodes ----------
    float sv = 0.f, sc = 0.f, ct = 0.f;
    if (lane < 32) {
        int loc = wnb + lane;
        int g = blk * BLK_NODES + loc;
        bool live = g < n;
        int ii = live ? g : (n - 1);
        unsigned long long pr = pairs[ii];
        int m1 = (int)(pr >> 32);
        int m2 = (int)(unsigned)pr;
        bool valid = m2 < n;
        int c1 = (m1 < n) ? m1 : (n - 1);
        int c2 = (m2 < n) ? m2 : (n - 1);
        float rp_ = radii[ii], r1_ = radii[c1], r2_ = radii[c2];
        float pr3 = rp_ * rp_ * rp_;
        float viol = fabsf(r1_ * r1_ * r1_ + r2_ * r2_ * r2_ - pr3) / pr3;
        bool active = live && valid && (types[ii] == 1);
        bool upd = active && (viol > VIOL_THRESH);
        float gate = upd ? corrArr[loc] : 0.f;
        if (live) gates[g] = 0.1f * gate;
        if (active) {
            sv = viol;
            sc = 1.0f / (1.0f + expf(-zArr[loc]));
            ct = 1.f;
        }
    }
#pragma unroll
    for (int off = 32; off > 0; off >>= 1) {
        sv += __shfl_down(sv, off);
        sc += __shfl_down(sc, off);
        ct += __shfl_down(ct, off);
    }
    if (lane == 0) {
        float4 p; p.x = sv; p.y = sc; p.z = ct; p.w = 0.f;
        partials[blk * 4 + w] = p;
    }
}

// pure streaming: out = feat + gates[node] * tanh(feat)
__global__ __launch_bounds__(256)
void update_kernel(const float* __restrict__ feat, const float* __restrict__ gates,
                   float* __restrict__ out, long total4) {
    long stride = (long)gridDim.x * blockDim.x;
    for (long t = (long)blockIdx.x * blockDim.x + threadIdx.x; t < total4; t += stride) {
        long base = t * 4;
        int node = (int)(base >> 6);          // F=64 floats per node
        float g = gates[node];
        float4 v = *(const float4*)(feat + base);
        float4 r;
        r.x = v.x + g * tanhf(v.x);
        r.y = v.y + g * tanhf(v.y);
        r.z = v.z + g * tanhf(v.z);
        r.w = v.w + g * tanhf(v.w);
        *(float4*)(out + base) = r;
    }
}

__global__ __launch_bounds__(256)
void finalize_kernel(const float4* __restrict__ partials, int np,
                     float* __restrict__ out_scalars) {
    __shared__ float red[3][4];
    int tid = threadIdx.x;
    float sv = 0.f, sc = 0.f, ct = 0.f;
    for (int i = tid; i < np; i += 256) {
        float4 p = partials[i];
        sv += p.x; sc += p.y; ct += p.z;
    }
#pragma unroll
    for (int off = 32; off > 0; off >>= 1) {
        sv += __shfl_down(sv, off);
        sc += __shfl_down(sc, off);
        ct += __shfl_down(ct, off);
    }
    int lane = tid & 63, w = tid >> 6;
    if (lane == 0) { red[0][w] = sv; red[1][w] = sc; red[2][w] = ct; }
    __syncthreads();
    if (tid == 0) {
        float tv = red[0][0] + red[0][1] + red[0][2] + red[0][3];
        float tc = red[1][0] + red[1][1] + red[1][2] + red[1][3];
        float tn = red[2][0] + red[2][1] + red[2][2] + red[2][3];
        float d = tn > 1.f ? tn : 1.f;
        out_scalars[0] = tv / d;
        out_scalars[1] = tc / d;
    }
}

extern "C" void kernel_launch(void* const* d_in, const int* in_sizes, int n_in,
                              void* d_out, int out_size, void* d_ws, size_t ws_size,
                              hipStream_t stream) {
    const float* feat  = (const float*)d_in[0];
    const float* radii = (const float*)d_in[1];
    const float* w1rc  = (const float*)d_in[2];
    const float* b1rc  = (const float*)d_in[3];
    const float* w2rc  = (const float*)d_in[4];
    const float* b2rc  = (const float*)d_in[5];
    const float* w3rc  = (const float*)d_in[6];
    const float* b3rc  = (const float*)d_in[7];
    const float* w1cp  = (const float*)d_in[8];
    const float* b1cp  = (const float*)d_in[9];
    const float* w2cp  = (const float*)d_in[10];
    const float* b2cp  = (const float*)d_in[11];
    const int*   eidx  = (const int*)d_in[12];
    const int*   types = (const int*)d_in[13];

    int n = in_sizes[0] / F;          // 300000
    int m = in_sizes[12] / 2;         // 3000000

    int nblocks = (n + BLK_NODES - 1) / BLK_NODES;
    int np = nblocks * 4;

    // ws layout: wt1t | wt2t | pairs | partials | gates | featbf
    char* ws = (char*)d_ws;
    short* wt1t = (short*)ws;                            ws += 128 * 192 * 2;
    short* wt2t = (short*)ws;                            ws += 48 * 128 * 2;
    unsigned long long* pairs = (unsigned long long*)ws; ws += (size_t)n * 8;
    float4* partials = (float4*)ws;                      ws += (size_t)np * 16;
    float* gates = (float*)ws;                           ws += (size_t)n * 4;
    short* featbf = (short*)ws;
    size_t featbf_bytes = (size_t)n * F * 2;
    bool useBF = ((size_t)(ws - (char*)d_ws) + featbf_bytes) <= ws_size;

    float* out         = (float*)d_out;
    float* out_scalars = out + (size_t)n * F;

    unsigned long long sent = ((unsigned long long)(unsigned)n << 32) | (unsigned)n;

    int bs = 256;
    init_kernel<<<(n + bs - 1) / bs, bs, 0, stream>>>(pairs, n, sent);
    prep_w1<<<dim3(128, 3), 64, 0, stream>>>(w1rc, w1cp, wt1t);
    prep_w2<<<dim3(48, 2), 64, 0, stream>>>(w2rc, w2cp, wt2t);
    if (useBF) {
        long total = (long)n * F;
        long nthr = total / 8;
        prep_feat<<<(unsigned)((nthr + bs - 1) / bs), bs, 0, stream>>>(feat, featbf, total);
    }
    int mt = (m + 3) / 4;
    edge_pair_kernel<<<(mt + bs - 1) / bs, bs, 0, stream>>>(eidx, eidx + m, pairs, m);
    if (useBF) {
        node_kernel<true><<<nblocks, bs, 0, stream>>>(
            feat, featbf, radii, b1rc, b2rc, w3rc, b3rc, b1cp, b2cp,
            wt1t, wt2t, types, pairs, gates, partials, n);
    } else {
        node_kernel<false><<<nblocks, bs, 0, stream>>>(
            feat, featbf, radii, b1rc, b2rc, w3rc, b3rc, b1cp, b2cp,
            wt1t, wt2t, types, pairs, gates, partials, n);
    }
    long total4 = (long)n * F / 4;
    update_kernel<<<2048, bs, 0, stream>>>(feat, gates, out, total4);
    finalize_kernel<<<1, 256, 0, stream>>>(partials, np, out_scalars);
}